// Round 5
// baseline (140.986 us; speedup 1.0000x reference)
//
#include <hip/hip_runtime.h>
#include <hip/hip_bf16.h>

#define B_N     2048
#define IN_N    512
#define SEQ_N   128
#define HID_N   12
#define HP_N    16
#define OUT_N   3

typedef __attribute__((ext_vector_type(8))) short short8;
typedef __attribute__((ext_vector_type(4))) float f32x4;
typedef unsigned int uint;
typedef unsigned short ushort;

__device__ __forceinline__ float fast_tanh(float x) {
    float e = __builtin_amdgcn_exp2f(x * 2.8853900817779268f);
    return 1.0f - 2.0f * __builtin_amdgcn_rcpf(e + 1.0f);
}

__device__ __forceinline__ ushort f2bf(float f) {   // RNE fp32->bf16
    uint u = __float_as_uint(f);
    u += 0x7fffu + ((u >> 16) & 1u);
    return (ushort)(u >> 16);
}

__device__ __forceinline__ float bf2f(ushort s) {
    return __uint_as_float(((uint)s) << 16);
}

// ---------------------------------------------------------------------------
// Prep: emb (512x128 f32) -> embB bf16;
// wP = B-fragments of w_ih_f / w_ih_r pre-packed in MFMA lane order:
//   wP[cks][src][l][j], value = w[h=l&15][i=(cks>>2)*128+(cks&3)*32+(l>>4)*8+j]
// ---------------------------------------------------------------------------
__global__ __launch_bounds__(256) void k_prep(
    const float* __restrict__ emb, const float* __restrict__ w_ih_f,
    const float* __restrict__ w_ih_r,
    ushort* __restrict__ embB, ushort* __restrict__ wP)
{
    int tid = blockIdx.x * 256 + threadIdx.x;      // 0..16383
    float4 e = ((const float4*)emb)[tid];
    uint2 o;
    o.x = (uint)f2bf(e.x) | ((uint)f2bf(e.y) << 16);
    o.y = (uint)f2bf(e.z) | ((uint)f2bf(e.w) << 16);
    ((uint2*)embB)[tid] = o;

    int j   = tid & 7;
    int l   = (tid >> 3) & 63;
    int src = (tid >> 9) & 1;
    int cks = tid >> 10;                           // 0..15
    int h   = l & 15;
    int i   = (cks >> 2) * 128 + (cks & 3) * 32 + (l >> 4) * 8 + j;
    const float* wsrc = src ? w_ih_r : w_ih_f;
    wP[(((size_t)cks * 2 + src) * 64 + l) * 8 + j] =
        (h < HID_N) ? f2bf(wsrc[h * IN_N + i]) : (ushort)0;
}

// ---------------------------------------------------------------------------
// k_pre v5: chunk-major phases + 2-deep gather pipeline.
//
// Phase p = c*4 + bq (c = chunk outer, bq = b inner).  Gather for phase p
// is issued at phase p-2 (R A/B buffers by parity); its idx words are
// loaded at phase p-3 (I A/B buffers) so gather issue never stalls on an
// address dependency.  Weights for chunk c are loaded from LDS once per
// 4 phases (was: every phase = 512 KB/block redundant LDS traffic).
// Accumulators: 4 static b-sets (a{0,1,R}_{0..3}).
// Barrier structure identical to v4 (publish lgkmcnt(0)+s_barrier, consume
// s_barrier; vmcnt NEVER drained in-loop).  Math bit-identical to v4.
// ---------------------------------------------------------------------------
__global__ __launch_bounds__(256, 2) void k_pre(
    const int* __restrict__ x, const ushort* __restrict__ embB,
    const ushort* __restrict__ wP,
    const float* __restrict__ b_ih_r, const float* __restrict__ b_hh_r,
    ushort* __restrict__ preB, float* __restrict__ rev)
{
    __shared__ __align__(16) ushort As[128 * 128];     // 32 KB
    __shared__ __align__(16) ushort wPs[16384];        // 32 KB

    const int t      = threadIdx.x;
    const int l      = t & 63;
    const int w      = t >> 6;
    const int lane16 = l & 15;
    const int quad   = l >> 4;
    const int il     = w * 32 + quad * 8;
    const int wg     = w * 4 + quad;
    const int l7     = lane16 & 7;
    const int so     = lane16 * 8;
    const int b0     = blockIdx.x * 4;

    // stage packed weights into LDS (once; drained by first publish barrier)
    {
        const uint4* s4 = (const uint4*)wP;
        uint4*       d4 = (uint4*)wPs;
        #pragma unroll
        for (int i = 0; i < 8; ++i) d4[t + i * 256] = s4[t + i * 256];
    }

    f32x4 a0_0={0.f,0.f,0.f,0.f}, a0_1={0.f,0.f,0.f,0.f}, a0_2={0.f,0.f,0.f,0.f}, a0_3={0.f,0.f,0.f,0.f};
    f32x4 a1_0={0.f,0.f,0.f,0.f}, a1_1={0.f,0.f,0.f,0.f}, a1_2={0.f,0.f,0.f,0.f}, a1_3={0.f,0.f,0.f,0.f};
    f32x4 aR_0={0.f,0.f,0.f,0.f}, aR_1={0.f,0.f,0.f,0.f}, aR_2={0.f,0.f,0.f,0.f}, aR_3={0.f,0.f,0.f,0.f};

    uint RA[8][4], RB[8][4];
    int4 IA0, IA1, IB0, IB1;

#define IDXLD(Ilo, Ihi, bq2, c2) do { \
    const int* xq_ = x + (size_t)(b0 + (bq2)) * IN_N + (c2) * 128 + il; \
    Ilo = *(const int4*)xq_;  Ihi = *(const int4*)(xq_ + 4); \
} while (0)

#define GFETCH(Rb, Ilo, Ihi) do { uint4 v_; \
    v_ = *(const uint4*)(embB + (size_t)(Ilo).x * SEQ_N + so); Rb[0][0]=v_.x; Rb[0][1]=v_.y; Rb[0][2]=v_.z; Rb[0][3]=v_.w; \
    v_ = *(const uint4*)(embB + (size_t)(Ilo).y * SEQ_N + so); Rb[1][0]=v_.x; Rb[1][1]=v_.y; Rb[1][2]=v_.z; Rb[1][3]=v_.w; \
    v_ = *(const uint4*)(embB + (size_t)(Ilo).z * SEQ_N + so); Rb[2][0]=v_.x; Rb[2][1]=v_.y; Rb[2][2]=v_.z; Rb[2][3]=v_.w; \
    v_ = *(const uint4*)(embB + (size_t)(Ilo).w * SEQ_N + so); Rb[3][0]=v_.x; Rb[3][1]=v_.y; Rb[3][2]=v_.z; Rb[3][3]=v_.w; \
    v_ = *(const uint4*)(embB + (size_t)(Ihi).x * SEQ_N + so); Rb[4][0]=v_.x; Rb[4][1]=v_.y; Rb[4][2]=v_.z; Rb[4][3]=v_.w; \
    v_ = *(const uint4*)(embB + (size_t)(Ihi).y * SEQ_N + so); Rb[5][0]=v_.x; Rb[5][1]=v_.y; Rb[5][2]=v_.z; Rb[5][3]=v_.w; \
    v_ = *(const uint4*)(embB + (size_t)(Ihi).z * SEQ_N + so); Rb[6][0]=v_.x; Rb[6][1]=v_.y; Rb[6][2]=v_.z; Rb[6][3]=v_.w; \
    v_ = *(const uint4*)(embB + (size_t)(Ihi).w * SEQ_N + so); Rb[7][0]=v_.x; Rb[7][1]=v_.y; Rb[7][2]=v_.z; Rb[7][3]=v_.w; \
} while (0)

#define PACKR(Rb) do { \
    _Pragma("unroll") \
    for (int pp = 0; pp < 8; ++pp) { \
        const uint sel_ = (pp & 1) ? 0x07060302u : 0x05040100u; \
        const int pv_ = pp >> 1; \
        uint u0_ = __builtin_amdgcn_perm(Rb[1][pv_], Rb[0][pv_], sel_); \
        uint u1_ = __builtin_amdgcn_perm(Rb[3][pv_], Rb[2][pv_], sel_); \
        uint u2_ = __builtin_amdgcn_perm(Rb[5][pv_], Rb[4][pv_], sel_); \
        uint u3_ = __builtin_amdgcn_perm(Rb[7][pv_], Rb[6][pv_], sel_); \
        const int s_    = lane16 * 8 + pp; \
        const int slot_ = wg ^ pp ^ l7; \
        *(uint4*)&As[(size_t)s_ * 128 + (size_t)slot_ * 8] = make_uint4(u0_, u1_, u2_, u3_); \
    } \
} while (0)

#define MMA(A0, A1, AR) do { \
    _Pragma("unroll") \
    for (int tt = 0; tt < 2; ++tt) { \
        const int row_ = (w * 2 + tt) * 16 + lane16; \
        const int fr_  = (row_ & 7) ^ ((row_ >> 3) & 7); \
        _Pragma("unroll") \
        for (int ks = 0; ks < 4; ++ks) { \
            const int slot_ = (ks * 4 + quad) ^ fr_; \
            short8 af_ = *(const short8*)&As[(size_t)row_ * 128 + (size_t)slot_ * 8]; \
            if (tt == 0) { A0 = __builtin_amdgcn_mfma_f32_16x16x32_bf16(af_, bfr[ks], A0, 0, 0, 0); } \
            else { A1 = __builtin_amdgcn_mfma_f32_16x16x32_bf16(af_, bfr[ks], A1, 0, 0, 0); \
                   AR = __builtin_amdgcn_mfma_f32_16x16x32_bf16(af_, bfrR[ks], AR, 0, 0, 0); } \
        } \
    } \
} while (0)

    // prologue: idx+gather phases 0,1 (latency exposed once); idx for phase 2
    IDXLD(IA0, IA1, 0, 0);
    IDXLD(IB0, IB1, 1, 0);
    GFETCH(RA, IA0, IA1);
    GFETCH(RB, IB0, IB1);
    IDXLD(IA0, IA1, 2, 0);

    for (int c = 0; c < 4; ++c) {
        short8 bfr[4], bfrR[4];
        #pragma unroll
        for (int bq = 0; bq < 4; ++bq) {
            // pack phase p (buffer parity bq&1); compiler emits counted vmcnt
            if (bq & 1) PACKR(RB); else PACKR(RA);

            // issue gather for phase p+2 into the buffer just consumed
            if (!(c == 3 && bq >= 2)) {
                if (bq & 1) GFETCH(RB, IB0, IB1); else GFETCH(RA, IA0, IA1);
            }
            // load idx for phase p+3 into the other I-buffer
            if (!(c == 3 && bq >= 1)) {
                if      (bq == 0) IDXLD(IB0, IB1, 3, c);
                else if (bq == 1) IDXLD(IA0, IA1, 0, c + 1);
                else if (bq == 2) IDXLD(IB0, IB1, 1, c + 1);
                else              IDXLD(IA0, IA1, 2, c + 1);
            }

            // publish As(p): LDS drain + raw barrier (NO vmcnt drain)
            asm volatile("s_waitcnt lgkmcnt(0)" ::: "memory");
            __builtin_amdgcn_s_barrier();
            __builtin_amdgcn_sched_barrier(0);

            // weights once per chunk (bq==0 only)
            if (bq == 0) {
                #pragma unroll
                for (int ks = 0; ks < 4; ++ks) {
                    const ushort* wp = wPs + (size_t)((c * 4 + ks) * 128 + l) * 8;
                    bfr[ks]  = *(const short8*)wp;
                    bfrR[ks] = *(const short8*)(wp + 512);
                }
            }

            if      (bq == 0) MMA(a0_0, a1_0, aR_0);
            else if (bq == 1) MMA(a0_1, a1_1, aR_1);
            else if (bq == 2) MMA(a0_2, a1_2, aR_2);
            else              MMA(a0_3, a1_3, aR_3);

            // consume barrier: As free for next pack
            asm volatile("" ::: "memory");
            __builtin_amdgcn_s_barrier();
            __builtin_amdgcn_sched_barrier(0);
        }
    }

#define EPI(bq, A0, A1, AR) do { \
    const int bcur_ = b0 + (bq); \
    _Pragma("unroll") \
    for (int r = 0; r < 4; ++r) { \
        const int s0_ = (w * 2 + 0) * 16 + quad * 4 + r; \
        preB[((size_t)bcur_ * SEQ_N + s0_) * HP_N + lane16] = f2bf(A0[r]); \
        const int s1_ = (w * 2 + 1) * 16 + quad * 4 + r; \
        preB[((size_t)bcur_ * SEQ_N + s1_) * HP_N + lane16] = f2bf(A1[r]); \
    } \
    if (w == 3 && quad == 3) \
        rev[bcur_ * HP_N + lane16] = fast_tanh(AR[3] + b_ih_r[lane16] + b_hh_r[lane16]); \
} while (0)

    if (lane16 < HID_N) {
        EPI(0, a0_0, a1_0, aR_0);
        EPI(1, a0_1, a1_1, aR_1);
        EPI(2, a0_2, a1_2, aR_2);
        EPI(3, a0_3, a1_3, aR_3);
    }
#undef IDXLD
#undef GFETCH
#undef PACKR
#undef MMA
#undef EPI
}

// ---------------------------------------------------------------------------
// k_rnn v2: two independent b-chains per 16-lane group (latency interleave).
// The 128-step recurrence is serial-latency-bound (~110 cy/step: bpermute +
// fma tree + tanh); two chains share W/bias registers and mutually hide
// each other's latency.  64 blocks x 256 thr, 32 b per block.
// ---------------------------------------------------------------------------
__global__ __launch_bounds__(256) void k_rnn(
    const ushort* __restrict__ preB, const float* __restrict__ rev,
    const float* __restrict__ w_hh_f,
    const float* __restrict__ b_ih_f, const float* __restrict__ b_hh_f,
    const float* __restrict__ fc_w, const float* __restrict__ fc_b,
    float* __restrict__ out)
{
    __shared__ float ho[32][40];

    const int tid = threadIdx.x;
    const int l   = tid & 63;
    const int j   = l & 15;
    const int jj  = (j < 12) ? j : 0;
    const int gid = tid >> 4;                 // 0..15 in block
    const int bA  = blockIdx.x * 32 + gid * 2;
    const int bB  = bA + 1;
    const int baseaddr = (l & 48) << 2;       // group-base lane * 4

    const float4* wr = (const float4*)(w_hh_f + jj * 12);
    float4 w0 = wr[0], w1 = wr[1], w2 = wr[2];
    float W[12] = {w0.x, w0.y, w0.z, w0.w, w1.x, w1.y, w1.z, w1.w,
                   w2.x, w2.y, w2.z, w2.w};
    const float bias = b_ih_f[jj] + b_hh_f[jj];

    const ushort* pbA = preB + (size_t)bA * SEQ_N * HP_N + j;
    const ushort* pbB = preB + (size_t)bB * SEQ_N * HP_N + j;
    ushort pqA[8], pqB[8];
    #pragma unroll
    for (int k = 0; k < 8; ++k) { pqA[k] = pbA[k * HP_N]; pqB[k] = pbB[k * HP_N]; }

    float hA = 0.f, hB = 0.f;
    for (int s8 = 0; s8 < 16; ++s8) {
        #pragma unroll
        for (int k = 0; k < 8; ++k) {
            int s = s8 * 8 + k;
            float pA = bf2f(pqA[k]) + bias;
            float pB = bf2f(pqB[k]) + bias;
            pqA[k] = pbA[((s + 8) & 127) * HP_N];   // branchless prefetch
            pqB[k] = pbB[((s + 8) & 127) * HP_N];
            int ha = __float_as_int(hA), hb = __float_as_int(hB);
            float hkA[12], hkB[12];
            #pragma unroll
            for (int kk = 0; kk < 12; ++kk) {
                hkA[kk] = __int_as_float(__builtin_amdgcn_ds_bpermute(baseaddr + 4 * kk, ha));
                hkB[kk] = __int_as_float(__builtin_amdgcn_ds_bpermute(baseaddr + 4 * kk, hb));
            }
            float cA0 = pA, cA1 = 0.f, cA2 = 0.f;
            float cB0 = pB, cB1 = 0.f, cB2 = 0.f;
            #pragma unroll
            for (int u = 0; u < 4; ++u) {
                cA0 = __builtin_fmaf(W[u],     hkA[u],     cA0);
                cA1 = __builtin_fmaf(W[4 + u], hkA[4 + u], cA1);
                cA2 = __builtin_fmaf(W[8 + u], hkA[8 + u], cA2);
                cB0 = __builtin_fmaf(W[u],     hkB[u],     cB0);
                cB1 = __builtin_fmaf(W[4 + u], hkB[4 + u], cB1);
                cB2 = __builtin_fmaf(W[8 + u], hkB[8 + u], cB2);
            }
            hA = fast_tanh(cA0 + cA1 + cA2);
            hB = fast_tanh(cB0 + cB1 + cB2);
        }
    }

    // epilogue FC (intra-wave LDS, no barrier needed)
    const int g2 = gid * 2;
    ho[g2][j]          = hA;
    ho[g2][20 + j]     = rev[bA * HP_N + j];
    ho[g2 + 1][j]      = hB;
    ho[g2 + 1][20 + j] = rev[bB * HP_N + j];
    if (j < OUT_N) {
        const float* fw = fc_w + j * 24;
        float oA = fc_b[j], oB = fc_b[j];
        #pragma unroll
        for (int k = 0; k < 12; ++k) {
            oA += fw[k] * ho[g2][k]     + fw[12 + k] * ho[g2][20 + k];
            oB += fw[k] * ho[g2 + 1][k] + fw[12 + k] * ho[g2 + 1][20 + k];
        }
        out[bA * OUT_N + j] = oA;
        out[bB * OUT_N + j] = oB;
    }
}

// ---------------------------------------------------------------------------
extern "C" void kernel_launch(void* const* d_in, const int* in_sizes, int n_in,
                              void* d_out, int out_size, void* d_ws, size_t ws_size,
                              hipStream_t stream) {
    const int*   x      = (const int*)  d_in[0];
    const float* emb    = (const float*)d_in[1];
    const float* w_ih_f = (const float*)d_in[2];
    const float* w_hh_f = (const float*)d_in[3];
    const float* b_ih_f = (const float*)d_in[4];
    const float* b_hh_f = (const float*)d_in[5];
    const float* w_ih_r = (const float*)d_in[6];
    const float* b_ih_r = (const float*)d_in[8];
    const float* b_hh_r = (const float*)d_in[9];
    const float* fc_w   = (const float*)d_in[10];
    const float* fc_b   = (const float*)d_in[11];
    float* out = (float*)d_out;

    ushort* preB = (ushort*)d_ws;                              // 8 MB
    float*  rev  = (float*)((char*)d_ws + 8388608);            // 128 KB
    ushort* embB = (ushort*)((char*)d_ws + 8519680);           // 128 KB
    ushort* wP   = (ushort*)((char*)d_ws + 8650752);           // 32 KB

    k_prep<<<64,    256, 0, stream>>>(emb, w_ih_f, w_ih_r, embB, wP);
    k_pre <<<B_N/4, 256, 0, stream>>>(x, embB, wP, b_ih_r, b_hh_r, preB, rev);
    k_rnn <<<B_N/32,256, 0, stream>>>(preB, rev, w_hh_f, b_ih_f, b_hh_f, fc_w, fc_b, out);
}

// Round 8
// 116.043 us; speedup vs baseline: 1.2149x; 1.2149x over previous
//
#include <hip/hip_runtime.h>
#include <hip/hip_bf16.h>

#define B_N     2048
#define IN_N    512
#define SEQ_N   128
#define HID_N   12
#define HP_N    16
#define OUT_N   3

typedef __attribute__((ext_vector_type(8))) short short8;
typedef __attribute__((ext_vector_type(4))) float f32x4;
typedef unsigned int uint;
typedef unsigned short ushort;

__device__ __forceinline__ float fast_tanh(float x) {
    float e = __builtin_amdgcn_exp2f(x * 2.8853900817779268f);
    return 1.0f - 2.0f * __builtin_amdgcn_rcpf(e + 1.0f);
}

__device__ __forceinline__ ushort f2bf(float f) {   // RNE fp32->bf16
    uint u = __float_as_uint(f);
    u += 0x7fffu + ((u >> 16) & 1u);
    return (ushort)(u >> 16);
}

__device__ __forceinline__ float bf2f(ushort s) {
    return __uint_as_float(((uint)s) << 16);
}

// ---------------------------------------------------------------------------
// Prep: emb (512x128 f32) -> embB bf16;
// wP = B-fragments of w_ih_f / w_ih_r pre-packed in MFMA lane order:
//   wP[cks][src][l][j], value = w[h=l&15][i=(cks>>2)*128+(cks&3)*32+(l>>4)*8+j]
// ---------------------------------------------------------------------------
__global__ __launch_bounds__(256) void k_prep(
    const float* __restrict__ emb, const float* __restrict__ w_ih_f,
    const float* __restrict__ w_ih_r,
    ushort* __restrict__ embB, ushort* __restrict__ wP)
{
    int tid = blockIdx.x * 256 + threadIdx.x;      // 0..16383
    float4 e = ((const float4*)emb)[tid];
    uint2 o;
    o.x = (uint)f2bf(e.x) | ((uint)f2bf(e.y) << 16);
    o.y = (uint)f2bf(e.z) | ((uint)f2bf(e.w) << 16);
    ((uint2*)embB)[tid] = o;

    int j   = tid & 7;
    int l   = (tid >> 3) & 63;
    int src = (tid >> 9) & 1;
    int cks = tid >> 10;                           // 0..15
    int h   = l & 15;
    int i   = (cks >> 2) * 128 + (cks & 3) * 32 + (l >> 4) * 8 + j;
    const float* wsrc = src ? w_ih_r : w_ih_f;
    wP[(((size_t)cks * 2 + src) * 64 + l) * 8 + j] =
        (h < HID_N) ? f2bf(wsrc[h * IN_N + i]) : (ushort)0;
}

// ---------------------------------------------------------------------------
// k_pre v5 (unchanged from round 5 — measured ~12.5 us):
// chunk-major phases + 2-deep gather pipeline, weights once per chunk,
// raw barriers (vmcnt never drained in-loop).  Math bit-identical to v4.
// ---------------------------------------------------------------------------
__global__ __launch_bounds__(256, 2) void k_pre(
    const int* __restrict__ x, const ushort* __restrict__ embB,
    const ushort* __restrict__ wP,
    const float* __restrict__ b_ih_r, const float* __restrict__ b_hh_r,
    ushort* __restrict__ preB, float* __restrict__ rev)
{
    __shared__ __align__(16) ushort As[128 * 128];     // 32 KB
    __shared__ __align__(16) ushort wPs[16384];        // 32 KB

    const int t      = threadIdx.x;
    const int l      = t & 63;
    const int w      = t >> 6;
    const int lane16 = l & 15;
    const int quad   = l >> 4;
    const int il     = w * 32 + quad * 8;
    const int wg     = w * 4 + quad;
    const int l7     = lane16 & 7;
    const int so     = lane16 * 8;
    const int b0     = blockIdx.x * 4;

    // stage packed weights into LDS (once; drained by first publish barrier)
    {
        const uint4* s4 = (const uint4*)wP;
        uint4*       d4 = (uint4*)wPs;
        #pragma unroll
        for (int i = 0; i < 8; ++i) d4[t + i * 256] = s4[t + i * 256];
    }

    f32x4 a0_0={0.f,0.f,0.f,0.f}, a0_1={0.f,0.f,0.f,0.f}, a0_2={0.f,0.f,0.f,0.f}, a0_3={0.f,0.f,0.f,0.f};
    f32x4 a1_0={0.f,0.f,0.f,0.f}, a1_1={0.f,0.f,0.f,0.f}, a1_2={0.f,0.f,0.f,0.f}, a1_3={0.f,0.f,0.f,0.f};
    f32x4 aR_0={0.f,0.f,0.f,0.f}, aR_1={0.f,0.f,0.f,0.f}, aR_2={0.f,0.f,0.f,0.f}, aR_3={0.f,0.f,0.f,0.f};

    uint RA[8][4], RB[8][4];
    int4 IA0, IA1, IB0, IB1;

#define IDXLD(Ilo, Ihi, bq2, c2) do { \
    const int* xq_ = x + (size_t)(b0 + (bq2)) * IN_N + (c2) * 128 + il; \
    Ilo = *(const int4*)xq_;  Ihi = *(const int4*)(xq_ + 4); \
} while (0)

#define GFETCH(Rb, Ilo, Ihi) do { uint4 v_; \
    v_ = *(const uint4*)(embB + (size_t)(Ilo).x * SEQ_N + so); Rb[0][0]=v_.x; Rb[0][1]=v_.y; Rb[0][2]=v_.z; Rb[0][3]=v_.w; \
    v_ = *(const uint4*)(embB + (size_t)(Ilo).y * SEQ_N + so); Rb[1][0]=v_.x; Rb[1][1]=v_.y; Rb[1][2]=v_.z; Rb[1][3]=v_.w; \
    v_ = *(const uint4*)(embB + (size_t)(Ilo).z * SEQ_N + so); Rb[2][0]=v_.x; Rb[2][1]=v_.y; Rb[2][2]=v_.z; Rb[2][3]=v_.w; \
    v_ = *(const uint4*)(embB + (size_t)(Ilo).w * SEQ_N + so); Rb[3][0]=v_.x; Rb[3][1]=v_.y; Rb[3][2]=v_.z; Rb[3][3]=v_.w; \
    v_ = *(const uint4*)(embB + (size_t)(Ihi).x * SEQ_N + so); Rb[4][0]=v_.x; Rb[4][1]=v_.y; Rb[4][2]=v_.z; Rb[4][3]=v_.w; \
    v_ = *(const uint4*)(embB + (size_t)(Ihi).y * SEQ_N + so); Rb[5][0]=v_.x; Rb[5][1]=v_.y; Rb[5][2]=v_.z; Rb[5][3]=v_.w; \
    v_ = *(const uint4*)(embB + (size_t)(Ihi).z * SEQ_N + so); Rb[6][0]=v_.x; Rb[6][1]=v_.y; Rb[6][2]=v_.z; Rb[6][3]=v_.w; \
    v_ = *(const uint4*)(embB + (size_t)(Ihi).w * SEQ_N + so); Rb[7][0]=v_.x; Rb[7][1]=v_.y; Rb[7][2]=v_.z; Rb[7][3]=v_.w; \
} while (0)

#define PACKR(Rb) do { \
    _Pragma("unroll") \
    for (int pp = 0; pp < 8; ++pp) { \
        const uint sel_ = (pp & 1) ? 0x07060302u : 0x05040100u; \
        const int pv_ = pp >> 1; \
        uint u0_ = __builtin_amdgcn_perm(Rb[1][pv_], Rb[0][pv_], sel_); \
        uint u1_ = __builtin_amdgcn_perm(Rb[3][pv_], Rb[2][pv_], sel_); \
        uint u2_ = __builtin_amdgcn_perm(Rb[5][pv_], Rb[4][pv_], sel_); \
        uint u3_ = __builtin_amdgcn_perm(Rb[7][pv_], Rb[6][pv_], sel_); \
        const int s_    = lane16 * 8 + pp; \
        const int slot_ = wg ^ pp ^ l7; \
        *(uint4*)&As[(size_t)s_ * 128 + (size_t)slot_ * 8] = make_uint4(u0_, u1_, u2_, u3_); \
    } \
} while (0)

#define MMA(A0, A1, AR) do { \
    _Pragma("unroll") \
    for (int tt = 0; tt < 2; ++tt) { \
        const int row_ = (w * 2 + tt) * 16 + lane16; \
        const int fr_  = (row_ & 7) ^ ((row_ >> 3) & 7); \
        _Pragma("unroll") \
        for (int ks = 0; ks < 4; ++ks) { \
            const int slot_ = (ks * 4 + quad) ^ fr_; \
            short8 af_ = *(const short8*)&As[(size_t)row_ * 128 + (size_t)slot_ * 8]; \
            if (tt == 0) { A0 = __builtin_amdgcn_mfma_f32_16x16x32_bf16(af_, bfr[ks], A0, 0, 0, 0); } \
            else { A1 = __builtin_amdgcn_mfma_f32_16x16x32_bf16(af_, bfr[ks], A1, 0, 0, 0); \
                   AR = __builtin_amdgcn_mfma_f32_16x16x32_bf16(af_, bfrR[ks], AR, 0, 0, 0); } \
        } \
    } \
} while (0)

    // prologue: idx+gather phases 0,1 (latency exposed once); idx for phase 2
    IDXLD(IA0, IA1, 0, 0);
    IDXLD(IB0, IB1, 1, 0);
    GFETCH(RA, IA0, IA1);
    GFETCH(RB, IB0, IB1);
    IDXLD(IA0, IA1, 2, 0);

    for (int c = 0; c < 4; ++c) {
        short8 bfr[4], bfrR[4];
        #pragma unroll
        for (int bq = 0; bq < 4; ++bq) {
            // pack phase p (buffer parity bq&1); compiler emits counted vmcnt
            if (bq & 1) PACKR(RB); else PACKR(RA);

            // issue gather for phase p+2 into the buffer just consumed
            if (!(c == 3 && bq >= 2)) {
                if (bq & 1) GFETCH(RB, IB0, IB1); else GFETCH(RA, IA0, IA1);
            }
            // load idx for phase p+3 into the other I-buffer
            if (!(c == 3 && bq >= 1)) {
                if      (bq == 0) IDXLD(IB0, IB1, 3, c);
                else if (bq == 1) IDXLD(IA0, IA1, 0, c + 1);
                else if (bq == 2) IDXLD(IB0, IB1, 1, c + 1);
                else              IDXLD(IA0, IA1, 2, c + 1);
            }

            // publish As(p): LDS drain + raw barrier (NO vmcnt drain)
            asm volatile("s_waitcnt lgkmcnt(0)" ::: "memory");
            __builtin_amdgcn_s_barrier();
            __builtin_amdgcn_sched_barrier(0);

            // weights once per chunk (bq==0 only)
            if (bq == 0) {
                #pragma unroll
                for (int ks = 0; ks < 4; ++ks) {
                    const ushort* wp = wPs + (size_t)((c * 4 + ks) * 128 + l) * 8;
                    bfr[ks]  = *(const short8*)wp;
                    bfrR[ks] = *(const short8*)(wp + 512);
                }
            }

            if      (bq == 0) MMA(a0_0, a1_0, aR_0);
            else if (bq == 1) MMA(a0_1, a1_1, aR_1);
            else if (bq == 2) MMA(a0_2, a1_2, aR_2);
            else              MMA(a0_3, a1_3, aR_3);

            // consume barrier: As free for next pack
            asm volatile("" ::: "memory");
            __builtin_amdgcn_s_barrier();
            __builtin_amdgcn_sched_barrier(0);
        }
    }

#define EPI(bq, A0, A1, AR) do { \
    const int bcur_ = b0 + (bq); \
    _Pragma("unroll") \
    for (int r = 0; r < 4; ++r) { \
        const int s0_ = (w * 2 + 0) * 16 + quad * 4 + r; \
        preB[((size_t)bcur_ * SEQ_N + s0_) * HP_N + lane16] = f2bf(A0[r]); \
        const int s1_ = (w * 2 + 1) * 16 + quad * 4 + r; \
        preB[((size_t)bcur_ * SEQ_N + s1_) * HP_N + lane16] = f2bf(A1[r]); \
    } \
    if (w == 3 && quad == 3) \
        rev[bcur_ * HP_N + lane16] = fast_tanh(AR[3] + b_ih_r[lane16] + b_hh_r[lane16]); \
} while (0)

    if (lane16 < HID_N) {
        EPI(0, a0_0, a1_0, aR_0);
        EPI(1, a0_1, a1_1, aR_1);
        EPI(2, a0_2, a1_2, aR_2);
        EPI(3, a0_3, a1_3, aR_3);
    }
#undef IDXLD
#undef GFETCH
#undef PACKR
#undef MMA
#undef EPI
}

// ---------------------------------------------------------------------------
// k_rnn v3: REVERT to the proven single-chain structure (16 lanes per b,
// 12 ds_bpermute broadcast, small live set).  v2's dual-chain needed ~60
// live VGPRs but was allocated 36 -> compiler serialized the 24 bpermutes
// (43.5 us).  One safe tweak vs v1: 256 blocks x 128 thr (8 b/block)
// covers all 256 CUs with 2 waves each instead of 128 CUs with 4.
// ---------------------------------------------------------------------------
__global__ __launch_bounds__(128) void k_rnn(
    const ushort* __restrict__ preB, const float* __restrict__ rev,
    const float* __restrict__ w_hh_f,
    const float* __restrict__ b_ih_f, const float* __restrict__ b_hh_f,
    const float* __restrict__ fc_w, const float* __restrict__ fc_b,
    float* __restrict__ out)
{
    __shared__ float ho[8][40];

    const int tid = threadIdx.x;
    const int l   = tid & 63;
    const int j   = l & 15;
    const int jj  = (j < 12) ? j : 0;
    const int gid = tid >> 4;                 // 0..7 in block
    const int b   = blockIdx.x * 8 + gid;
    const int baseaddr = (l & 48) << 2;       // group-base lane * 4

    const float4* wr = (const float4*)(w_hh_f + jj * 12);
    float4 w0 = wr[0], w1 = wr[1], w2 = wr[2];
    float W[12] = {w0.x, w0.y, w0.z, w0.w, w1.x, w1.y, w1.z, w1.w,
                   w2.x, w2.y, w2.z, w2.w};
    const float bias = b_ih_f[jj] + b_hh_f[jj];

    const ushort* pb = preB + (size_t)b * SEQ_N * HP_N + j;
    ushort pq[8];
    #pragma unroll
    for (int k = 0; k < 8; ++k) pq[k] = pb[k * HP_N];

    float h = 0.f;
    for (int s8 = 0; s8 < 16; ++s8) {
        #pragma unroll
        for (int k = 0; k < 8; ++k) {
            int s = s8 * 8 + k;
            float p = bf2f(pq[k]) + bias;
            pq[k] = pb[((s + 8) & 127) * HP_N];     // branchless prefetch
            int hb = __float_as_int(h);
            float hk[12];
            #pragma unroll
            for (int kk = 0; kk < 12; ++kk)
                hk[kk] = __int_as_float(__builtin_amdgcn_ds_bpermute(baseaddr + 4 * kk, hb));
            float c0 = p, c1 = 0.f, c2 = 0.f;
            #pragma unroll
            for (int u = 0; u < 4; ++u) {
                c0 = __builtin_fmaf(W[u],     hk[u],     c0);
                c1 = __builtin_fmaf(W[4 + u], hk[4 + u], c1);
                c2 = __builtin_fmaf(W[8 + u], hk[8 + u], c2);
            }
            h = fast_tanh(c0 + c1 + c2);
        }
    }

    // epilogue FC (intra-wave LDS, no barrier needed)
    ho[gid][j]      = h;
    ho[gid][20 + j] = rev[b * HP_N + j];
    if (j < OUT_N) {
        const float* fw = fc_w + j * 24;
        float o = fc_b[j];
        #pragma unroll
        for (int k = 0; k < 12; ++k)
            o += fw[k] * ho[gid][k] + fw[12 + k] * ho[gid][20 + k];
        out[b * OUT_N + j] = o;
    }
}

// ---------------------------------------------------------------------------
extern "C" void kernel_launch(void* const* d_in, const int* in_sizes, int n_in,
                              void* d_out, int out_size, void* d_ws, size_t ws_size,
                              hipStream_t stream) {
    const int*   x      = (const int*)  d_in[0];
    const float* emb    = (const float*)d_in[1];
    const float* w_ih_f = (const float*)d_in[2];
    const float* w_hh_f = (const float*)d_in[3];
    const float* b_ih_f = (const float*)d_in[4];
    const float* b_hh_f = (const float*)d_in[5];
    const float* w_ih_r = (const float*)d_in[6];
    const float* b_ih_r = (const float*)d_in[8];
    const float* b_hh_r = (const float*)d_in[9];
    const float* fc_w   = (const float*)d_in[10];
    const float* fc_b   = (const float*)d_in[11];
    float* out = (float*)d_out;

    ushort* preB = (ushort*)d_ws;                              // 8 MB
    float*  rev  = (float*)((char*)d_ws + 8388608);            // 128 KB
    ushort* embB = (ushort*)((char*)d_ws + 8519680);           // 128 KB
    ushort* wP   = (ushort*)((char*)d_ws + 8650752);           // 32 KB

    k_prep<<<64,    256, 0, stream>>>(emb, w_ih_f, w_ih_r, embB, wP);
    k_pre <<<B_N/4, 256, 0, stream>>>(x, embB, wP, b_ih_r, b_hh_r, preB, rev);
    k_rnn <<<B_N/8, 128, 0, stream>>>(preB, rev, w_hh_f, b_ih_f, b_hh_f, fc_w, fc_b, out);
}